// Round 1
// baseline (940.083 us; speedup 1.0000x reference)
//
#include <hip/hip_runtime.h>
#include <math.h>

#define NN 4096
#define HID 256
#define MD 32
#define NH 8
#define SCALE 0.17677669529663687f  // 1/sqrt(32)

#define MSPLIT 4
#define MRANGE (NN / MSPLIT)  // 1024
#define BM 32                 // m chunk per LDS stage
// LDS head-major K/V layout: addr = h*KH + ml*KJ + j
// KJ=36 (row pad, 144B, 16B-aligned), KH=1156 (== 4 mod 32 -> h groups hit
// disjoint bank quads; 4624B, 16B-aligned). size = 8*1156 = 9248 floats.
#define KJ 36
#define KH 1156

// ---------------- projections: Q=NF@Wq+bq, K=NF@Wk+bk, V=MSG@Wv+bv --------
__global__ __launch_bounds__(256) void proj_kernel(
    const float* __restrict__ nf, const float* __restrict__ msg,
    const float* __restrict__ Wq, const float* __restrict__ bq,
    const float* __restrict__ Wk, const float* __restrict__ bk,
    const float* __restrict__ Wv, const float* __restrict__ bv,
    float* __restrict__ Qo, float* __restrict__ Ko, float* __restrict__ Vo)
{
    __shared__ __align__(16) float in_lds[32 * 256];
    const int b = blockIdx.x;
    const int which = b >> 7;     // 0:Q 1:K 2:V (128 blocks each)
    const int nb = b & 127;
    const float* in; const float* W; const float* bias; float* out; int KD;
    if (which == 0)      { in = nf;  W = Wq; bias = bq; out = Qo; KD = 256; }
    else if (which == 1) { in = nf;  W = Wk; bias = bk; out = Ko; KD = 256; }
    else                 { in = msg; W = Wv; bias = bv; out = Vo; KD = 32;  }
    const int t = threadIdx.x;
    const int n4 = (32 * KD) >> 2;
    const float4* src = (const float4*)(in + (size_t)nb * 32 * KD);
    for (int i = t; i < n4; i += 256) ((float4*)in_lds)[i] = src[i];
    __syncthreads();

    float acc[32];
    #pragma unroll
    for (int r = 0; r < 32; ++r) acc[r] = 0.f;
    for (int k = 0; k < KD; ++k) {
        float w = W[k * 256 + t];        // coalesced; in_lds read is broadcast
        #pragma unroll
        for (int r = 0; r < 32; ++r) acc[r] += in_lds[r * KD + k] * w;
    }
    const float bb = bias[t];
    #pragma unroll
    for (int r = 0; r < 32; ++r) out[(size_t)(nb * 32 + r) * 256 + t] = acc[r] + bb;
}

// ---------------- pass 1: L[n,h] = sum_m adj * exp(scale * Q.K) ----------
__global__ __launch_bounds__(256) void lpass_kernel(
    const float* __restrict__ Q, const float* __restrict__ K,
    const int* __restrict__ adj, float* __restrict__ Lpart)
{
    __shared__ __align__(16) float kbuf[8 * KH];
    __shared__ unsigned char adj_lds[32 * 33];
    const int nb = blockIdx.x;
    const int ms = blockIdx.y;
    const int t = threadIdx.x;
    const int h = t & 7, nl = t >> 3;
    const int n = nb * 32 + nl;

    // stage Q rows (linear) into kbuf, pull my (n,h) fragment, pre-scale
    const float4* qsrc = (const float4*)(Q + (size_t)nb * 32 * 256);
    for (int i = t; i < 2048; i += 256) ((float4*)kbuf)[i] = qsrc[i];
    __syncthreads();
    float4 q4[8];
    #pragma unroll
    for (int j = 0; j < 8; ++j) {
        float4 v = *(const float4*)(kbuf + nl * 256 + h * 32 + j * 4);
        q4[j].x = v.x * SCALE; q4[j].y = v.y * SCALE;
        q4[j].z = v.z * SCALE; q4[j].w = v.w * SCALE;
    }
    __syncthreads();

    float l = 0.f;
    const int mstart = ms * MRANGE;
    for (int mc = 0; mc < MRANGE / BM; ++mc) {
        const int mb = mstart + mc * BM;
        for (int i = t; i < 2048; i += 256) {        // K chunk -> head-major
            int flat = i * 4;
            int ml = flat >> 8, c = flat & 255;
            int hh = c >> 5, j = c & 31;
            float4 v = *(const float4*)(K + (size_t)(mb + ml) * 256 + c);
            *(float4*)(kbuf + hh * KH + ml * KJ + j) = v;
        }
        for (int i = t; i < 1024; i += 256) {
            int r = i >> 5, c = i & 31;
            adj_lds[r * 33 + c] =
                (unsigned char)adj[(size_t)(nb * 32 + r) * NN + mb + c];
        }
        __syncthreads();
        const float* kp = kbuf + h * KH;
        #pragma unroll 4
        for (int ml = 0; ml < BM; ++ml) {
            const float* kr = kp + ml * KJ;
            float s = 0.f;
            #pragma unroll
            for (int j = 0; j < 8; ++j) {
                float4 kv = *(const float4*)(kr + j * 4);
                s += q4[j].x * kv.x + q4[j].y * kv.y
                   + q4[j].z * kv.z + q4[j].w * kv.w;
            }
            float e = __expf(s);
            l += adj_lds[nl * 33 + ml] ? e : 0.f;
        }
        __syncthreads();
    }
    Lpart[((size_t)ms * NN + n) * 8 + h] = l;
}

// -------- pass 2: recompute p, write attn_mean + PV partials -------------
__global__ __launch_bounds__(256) void opass_kernel(
    const float* __restrict__ Q, const float* __restrict__ K,
    const float* __restrict__ V, const int* __restrict__ adj,
    const float* __restrict__ Lpart, float* __restrict__ accpart,
    float* __restrict__ amean)
{
    __shared__ __align__(16) float kbuf[8 * KH];
    __shared__ __align__(16) float vbuf[8 * KH];
    __shared__ float am[32 * 33];
    __shared__ unsigned char adj_lds[32 * 33];
    const int nb = blockIdx.x;
    const int ms = blockIdx.y;
    const int t = threadIdx.x;
    const int h = t & 7, nl = t >> 3;
    const int n = nb * 32 + nl;

    float L = 0.f;
    #pragma unroll
    for (int s2 = 0; s2 < MSPLIT; ++s2) L += Lpart[((size_t)s2 * NN + n) * 8 + h];
    const float rcpL = 1.0f / L;

    const float4* qsrc = (const float4*)(Q + (size_t)nb * 32 * 256);
    for (int i = t; i < 2048; i += 256) ((float4*)kbuf)[i] = qsrc[i];
    __syncthreads();
    float4 q4[8];
    #pragma unroll
    for (int j = 0; j < 8; ++j) {
        float4 v = *(const float4*)(kbuf + nl * 256 + h * 32 + j * 4);
        q4[j].x = v.x * SCALE; q4[j].y = v.y * SCALE;
        q4[j].z = v.z * SCALE; q4[j].w = v.w * SCALE;
    }
    __syncthreads();

    float4 acc4[8];
    #pragma unroll
    for (int j = 0; j < 8; ++j) acc4[j] = make_float4(0.f, 0.f, 0.f, 0.f);

    const int mstart = ms * MRANGE;
    for (int mc = 0; mc < MRANGE / BM; ++mc) {
        const int mb = mstart + mc * BM;
        for (int i = t; i < 2048; i += 256) {
            int flat = i * 4;
            int ml = flat >> 8, c = flat & 255;
            int hh = c >> 5, j = c & 31;
            *(float4*)(kbuf + hh * KH + ml * KJ + j) =
                *(const float4*)(K + (size_t)(mb + ml) * 256 + c);
            *(float4*)(vbuf + hh * KH + ml * KJ + j) =
                *(const float4*)(V + (size_t)(mb + ml) * 256 + c);
        }
        for (int i = t; i < 1024; i += 256) {
            int r = i >> 5, c = i & 31;
            adj_lds[r * 33 + c] =
                (unsigned char)adj[(size_t)(nb * 32 + r) * NN + mb + c];
        }
        __syncthreads();
        const float* kp = kbuf + h * KH;
        const float* vp = vbuf + h * KH;
        #pragma unroll 2
        for (int ml = 0; ml < BM; ++ml) {
            const float* kr = kp + ml * KJ;
            float s = 0.f;
            #pragma unroll
            for (int j = 0; j < 8; ++j) {
                float4 kv = *(const float4*)(kr + j * 4);
                s += q4[j].x * kv.x + q4[j].y * kv.y
                   + q4[j].z * kv.z + q4[j].w * kv.w;
            }
            float e = __expf(s);
            float p = adj_lds[nl * 33 + ml] ? e : 0.f;
            const float* vr = vp + ml * KJ;
            #pragma unroll
            for (int j = 0; j < 8; ++j) {
                float4 vv = *(const float4*)(vr + j * 4);
                acc4[j].x += p * vv.x; acc4[j].y += p * vv.y;
                acc4[j].z += p * vv.z; acc4[j].w += p * vv.w;
            }
            float a = p * rcpL;
            a += __shfl_xor(a, 1);
            a += __shfl_xor(a, 2);
            a += __shfl_xor(a, 4);
            if (h == 0) am[nl * 33 + ml] = a * 0.125f;
        }
        __syncthreads();
        for (int i = t; i < 1024; i += 256) {   // coalesced attn_mean write
            int r = i >> 5, c = i & 31;
            amean[(size_t)(nb * 32 + r) * NN + mb + c] = am[r * 33 + c];
        }
        // next stage overwrites kbuf/vbuf (safe: compute done at barrier);
        // am is re-written only after the next barrier.
    }
    float* ap = accpart + ((size_t)ms * NN + n) * 256 + h * 32;
    #pragma unroll
    for (int j = 0; j < 8; ++j) {
        float4 o;
        o.x = acc4[j].x * rcpL; o.y = acc4[j].y * rcpL;
        o.z = acc4[j].z * rcpL; o.w = acc4[j].w * rcpL;
        ((float4*)ap)[j] = o;
    }
}

// -------- finalize: routed = (sum_ms accpart) @ Wo + bo ------------------
__global__ __launch_bounds__(256) void final_kernel(
    const float* __restrict__ accpart, const float* __restrict__ Wo,
    const float* __restrict__ bo, float* __restrict__ routed)
{
    __shared__ float sacc[32 * 257];
    const int nb = blockIdx.x, t = threadIdx.x;
    for (int i = t; i < 8192; i += 256) {
        int r = i >> 8, c = i & 255;
        int n = nb * 32 + r;
        float s = 0.f;
        #pragma unroll
        for (int ms = 0; ms < MSPLIT; ++ms)
            s += accpart[((size_t)ms * NN + n) * 256 + c];
        sacc[r * 257 + c] = s;
    }
    __syncthreads();
    const int j = t & 31, r0 = t >> 5;
    #pragma unroll
    for (int rr = 0; rr < 4; ++rr) {
        int r = r0 * 4 + rr;
        float s = bo[j];
        for (int i = 0; i < 256; ++i) s += sacc[r * 257 + i] * Wo[i * 32 + j];
        routed[(size_t)(nb * 32 + r) * 32 + j] = s;
    }
}

extern "C" void kernel_launch(void* const* d_in, const int* in_sizes, int n_in,
                              void* d_out, int out_size, void* d_ws, size_t ws_size,
                              hipStream_t stream) {
    const float* nf  = (const float*)d_in[0];
    const float* msg = (const float*)d_in[1];
    const int*   adj = (const int*)d_in[2];
    const float* Wq  = (const float*)d_in[3];
    const float* bq  = (const float*)d_in[4];
    const float* Wk  = (const float*)d_in[5];
    const float* bk  = (const float*)d_in[6];
    const float* Wv  = (const float*)d_in[7];
    const float* bv  = (const float*)d_in[8];
    const float* Wo  = (const float*)d_in[9];
    const float* bo  = (const float*)d_in[10];

    float* routed = (float*)d_out;
    float* amean  = (float*)d_out + (size_t)NN * MD;

    float* ws = (float*)d_ws;
    float* Q  = ws;                    // 4096*256
    float* K  = ws + 1048576;          // 4096*256
    float* V  = ws + 2097152;          // 4096*256
    float* Lp = ws + 3145728;          // MSPLIT*4096*8
    float* ap = ws + 3276800;          // MSPLIT*4096*256

    proj_kernel<<<384, 256, 0, stream>>>(nf, msg, Wq, bq, Wk, bk, Wv, bv, Q, K, V);
    lpass_kernel<<<dim3(128, MSPLIT), 256, 0, stream>>>(Q, K, adj, Lp);
    opass_kernel<<<dim3(128, MSPLIT), 256, 0, stream>>>(Q, K, V, adj, Lp, ap, amean);
    final_kernel<<<128, 256, 0, stream>>>(ap, Wo, bo, routed);
}

// Round 2
// 257.636 us; speedup vs baseline: 3.6489x; 3.6489x over previous
//
#include <hip/hip_runtime.h>
#include <math.h>

#define NN 4096
#define HID 256
#define MD 32
#define NH 8
#define SCALE 0.17677669529663687f  // 1/sqrt(32)

typedef float f32x4 __attribute__((ext_vector_type(4)));
typedef short bf16x8 __attribute__((ext_vector_type(8)));

__device__ inline unsigned int bfr(float x) {             // f32 -> bf16 bits (RNE)
    unsigned int u = __float_as_uint(x);
    return (u + 0x7fffu + ((u >> 16) & 1u)) >> 16;
}
__device__ inline unsigned int pkbf(float a, float b) {   // pack 2 bf16 into u32
    return bfr(a) | (bfr(b) << 16);
}

// ---------------- projections: Q=NF@Wq+bq, K=NF@Wk+bk, V=MSG@Wv+bv --------
__global__ __launch_bounds__(256) void proj_kernel(
    const float* __restrict__ nf, const float* __restrict__ msg,
    const float* __restrict__ Wq, const float* __restrict__ bq,
    const float* __restrict__ Wk, const float* __restrict__ bk,
    const float* __restrict__ Wv, const float* __restrict__ bv,
    float* __restrict__ Qo, float* __restrict__ Ko, float* __restrict__ Vo)
{
    __shared__ __align__(16) float in_lds[32 * 256];
    const int b = blockIdx.x;
    const int which = b >> 7;     // 0:Q 1:K 2:V (128 blocks each)
    const int nb = b & 127;
    const float* in; const float* W; const float* bias; float* out; int KD;
    if (which == 0)      { in = nf;  W = Wq; bias = bq; out = Qo; KD = 256; }
    else if (which == 1) { in = nf;  W = Wk; bias = bk; out = Ko; KD = 256; }
    else                 { in = msg; W = Wv; bias = bv; out = Vo; KD = 32;  }
    const int t = threadIdx.x;
    const int n4 = (32 * KD) >> 2;
    const float4* src = (const float4*)(in + (size_t)nb * 32 * KD);
    for (int i = t; i < n4; i += 256) ((float4*)in_lds)[i] = src[i];
    __syncthreads();

    float acc[32];
    #pragma unroll
    for (int r = 0; r < 32; ++r) acc[r] = 0.f;
    for (int k = 0; k < KD; ++k) {
        float w = W[k * 256 + t];
        #pragma unroll
        for (int r = 0; r < 32; ++r) acc[r] += in_lds[r * KD + k] * w;
    }
    const float bb = bias[t];
    #pragma unroll
    for (int r = 0; r < 32; ++r) out[(size_t)(nb * 32 + r) * 256 + t] = acc[r] + bb;
}

// ------------- pack adjacency into bitmask: abit[n][64] u64 ---------------
__global__ __launch_bounds__(256) void abit_kernel(
    const int* __restrict__ adj, unsigned long long* __restrict__ abit)
{
    const int n = blockIdx.x * 4 + (threadIdx.x >> 6);
    const int l = threadIdx.x & 63;
    for (int j = 0; j < 64; ++j) {
        int v = adj[(size_t)n * NN + j * 64 + l];
        unsigned long long m = __ballot(v != 0);
        if (l == 0) abit[(size_t)n * 64 + j] = m;
    }
}

// -------- pack Q,K f32[n][256] -> bf16 head-major [h][n][32] --------------
__global__ __launch_bounds__(256) void pack_qk(
    const float* __restrict__ Qf, const float* __restrict__ Kf,
    unsigned short* __restrict__ Qb, unsigned short* __restrict__ Kb)
{
    int i = blockIdx.x * 256 + threadIdx.x;     // 0..262143
    int isK = i >= 131072;
    int j = i & 131071;                          // (n, c8)
    int n = j >> 5, c8 = j & 31;
    const float* src = (isK ? Kf : Qf) + (size_t)n * 256 + c8 * 8;
    float4 a = ((const float4*)src)[0];
    float4 b = ((const float4*)src)[1];
    float sc = isK ? 1.0f : SCALE;
    a.x *= sc; a.y *= sc; a.z *= sc; a.w *= sc;
    b.x *= sc; b.y *= sc; b.z *= sc; b.w *= sc;
    int h = c8 >> 2, d = (c8 & 3) * 8;
    unsigned short* dst = (isK ? Kb : Qb) + (((size_t)h * NN + n) << 5) + d;
    uint4 o;
    o.x = pkbf(a.x, a.y); o.y = pkbf(a.z, a.w);
    o.z = pkbf(b.x, b.y); o.w = pkbf(b.z, b.w);
    *(uint4*)dst = o;
}

// -------- pack V f32[m][256] -> bf16 transposed Vt[h][d][m] ---------------
__global__ __launch_bounds__(256) void pack_vt(
    const float* __restrict__ Vf, unsigned short* __restrict__ Vt)
{
    __shared__ __align__(16) float lds[128 * 33];
    const int h = blockIdx.x >> 5, mt = blockIdx.x & 31;  // m-tile of 128
    const int t = threadIdx.x;
    for (int k = 0; k < 4; ++k) {
        int flat = k * 256 + t;            // 0..1023 float4 slots
        int row = flat >> 3, c4 = flat & 7;
        float4 v = *(const float4*)(Vf + (size_t)(mt * 128 + row) * 256 + h * 32 + c4 * 4);
        lds[row * 33 + c4 * 4 + 0] = v.x;
        lds[row * 33 + c4 * 4 + 1] = v.y;
        lds[row * 33 + c4 * 4 + 2] = v.z;
        lds[row * 33 + c4 * 4 + 3] = v.w;
    }
    __syncthreads();
    const int d = t >> 3, mq = t & 7;      // each writes 16 m for one d
    #pragma unroll
    for (int k = 0; k < 2; ++k) {
        int m0 = mq * 16 + k * 8;
        uint4 o;
        o.x = pkbf(lds[(m0 + 0) * 33 + d], lds[(m0 + 1) * 33 + d]);
        o.y = pkbf(lds[(m0 + 2) * 33 + d], lds[(m0 + 3) * 33 + d]);
        o.z = pkbf(lds[(m0 + 4) * 33 + d], lds[(m0 + 5) * 33 + d]);
        o.w = pkbf(lds[(m0 + 6) * 33 + d], lds[(m0 + 7) * 33 + d]);
        *(uint4*)(Vt + ((size_t)(h * 32 + d)) * NN + mt * 128 + m0) = o;
    }
}

// ---------------- sweep 1: L partials via MFMA QK^T -----------------------
// block: (ntile, msgroup); wave w -> msplit = msgroup*4+w, m range 256
__global__ __launch_bounds__(256, 4) void sweep1_kernel(
    const unsigned short* __restrict__ Qb, const unsigned short* __restrict__ Kb,
    const unsigned int* __restrict__ abit, float* __restrict__ Lpart)
{
    const int ntile = blockIdx.x, msg = blockIdx.y;
    const int t = threadIdx.x;
    const int w = t >> 6, l = t & 63;
    const int g = l >> 4, q = l & 15;
    const int ms = msg * 4 + w;
    const int n0 = ntile * 16;
    const int mbase = ms * 256;

    bf16x8 qf[8];
    #pragma unroll
    for (int h = 0; h < 8; ++h)
        qf[h] = *(const bf16x8*)(Qb + (((size_t)h * NN + n0 + q) << 5) + g * 8);

    float lacc[8];
    #pragma unroll
    for (int h = 0; h < 8; ++h) lacc[h] = 0.f;

    for (int ch = 0; ch < 8; ++ch) {
        const int mb = mbase + ch * 32;
        const unsigned int wbits = abit[(size_t)(n0 + q) * 128 + (mb >> 5)];
        #pragma unroll
        for (int h = 0; h < 8; ++h) {
            bf16x8 ka0 = *(const bf16x8*)(Kb + (((size_t)h * NN + mb + q) << 5) + g * 8);
            bf16x8 ka1 = *(const bf16x8*)(Kb + (((size_t)h * NN + mb + 16 + q) << 5) + g * 8);
            f32x4 z = {0.f, 0.f, 0.f, 0.f};
            f32x4 s0 = __builtin_amdgcn_mfma_f32_16x16x32_bf16(ka0, qf[h], z, 0, 0, 0);
            f32x4 s1 = __builtin_amdgcn_mfma_f32_16x16x32_bf16(ka1, qf[h], z, 0, 0, 0);
            #pragma unroll
            for (int r = 0; r < 4; ++r) {
                float e0 = __expf(s0[r]);
                float e1 = __expf(s1[r]);
                lacc[h] += ((wbits >> (4 * g + r)) & 1u) ? e0 : 0.f;
                lacc[h] += ((wbits >> (16 + 4 * g + r)) & 1u) ? e1 : 0.f;
            }
        }
    }
    #pragma unroll
    for (int h = 0; h < 8; ++h) {
        float v = lacc[h];
        v += __shfl_xor(v, 16);
        v += __shfl_xor(v, 32);
        if (g == 0) Lpart[(size_t)ms * 32768 + h * NN + n0 + q] = v;
    }
}

// ---------------- Linv[h][n] = 1 / sum_ms Lpart ---------------------------
__global__ __launch_bounds__(256) void linv_kernel(
    const float* __restrict__ Lpart, float* __restrict__ Linv)
{
    int i = blockIdx.x * 256 + threadIdx.x;   // 0..32767
    float s = 0.f;
    #pragma unroll
    for (int ms = 0; ms < 16; ++ms) s += Lpart[(size_t)ms * 32768 + i];
    Linv[i] = 1.0f / s;
}

// ---------------- sweep 2: amean + PV partials via MFMA -------------------
__global__ __launch_bounds__(256, 2) void sweep2_kernel(
    const unsigned short* __restrict__ Qb, const unsigned short* __restrict__ Kb,
    const unsigned short* __restrict__ Vt, const unsigned int* __restrict__ abit,
    const float* __restrict__ Linv, float* __restrict__ Opart,
    float* __restrict__ amean)
{
    __shared__ __align__(16) float Ow[2 * 16 * 260];
    __shared__ unsigned int Ppk[4 * 272];
    const int ntile = blockIdx.x, msg = blockIdx.y;
    const int t = threadIdx.x;
    const int w = t >> 6, l = t & 63;
    const int g = l >> 4, q = l & 15;
    const int ms = msg * 4 + w;
    const int n0 = ntile * 16;
    const int mbase = ms * 256;
    unsigned int* pp = Ppk + w * 272;

    bf16x8 qf[8];
    float rL[8];
    #pragma unroll
    for (int h = 0; h < 8; ++h) {
        qf[h] = *(const bf16x8*)(Qb + (((size_t)h * NN + n0 + q) << 5) + g * 8);
        rL[h] = Linv[h * NN + n0 + q];
    }
    f32x4 o[8][2];
    #pragma unroll
    for (int h = 0; h < 8; ++h) {
        o[h][0] = (f32x4){0.f, 0.f, 0.f, 0.f};
        o[h][1] = (f32x4){0.f, 0.f, 0.f, 0.f};
    }

    for (int ch = 0; ch < 8; ++ch) {
        const int mb = mbase + ch * 32;
        const unsigned int wbits = abit[(size_t)(n0 + q) * 128 + (mb >> 5)];
        float am[8];
        #pragma unroll
        for (int r = 0; r < 8; ++r) am[r] = 0.f;

        #pragma unroll
        for (int h = 0; h < 8; ++h) {
            bf16x8 ka0 = *(const bf16x8*)(Kb + (((size_t)h * NN + mb + q) << 5) + g * 8);
            bf16x8 ka1 = *(const bf16x8*)(Kb + (((size_t)h * NN + mb + 16 + q) << 5) + g * 8);
            f32x4 z = {0.f, 0.f, 0.f, 0.f};
            f32x4 s0 = __builtin_amdgcn_mfma_f32_16x16x32_bf16(ka0, qf[h], z, 0, 0, 0);
            f32x4 s1 = __builtin_amdgcn_mfma_f32_16x16x32_bf16(ka1, qf[h], z, 0, 0, 0);
            float pn[8];
            #pragma unroll
            for (int r = 0; r < 4; ++r) {
                float e0 = __expf(s0[r]) * rL[h];
                float e1 = __expf(s1[r]) * rL[h];
                pn[r]     = ((wbits >> (4 * g + r)) & 1u) ? e0 : 0.f;
                pn[4 + r] = ((wbits >> (16 + 4 * g + r)) & 1u) ? e1 : 0.f;
                am[r] += pn[r];
                am[4 + r] += pn[4 + r];
            }
            // pair-pack P into per-wave LDS tile (m-pair major, stride 17)
            pp[(2 * g + 0) * 17 + q] = pkbf(pn[0], pn[1]);
            pp[(2 * g + 1) * 17 + q] = pkbf(pn[2], pn[3]);
            pp[(8 + 2 * g + 0) * 17 + q] = pkbf(pn[4], pn[5]);
            pp[(8 + 2 * g + 1) * 17 + q] = pkbf(pn[6], pn[7]);
            __builtin_amdgcn_wave_barrier();
            union { unsigned int u[4]; bf16x8 v; } pu;
            pu.u[0] = pp[(4 * g + 0) * 17 + q];
            pu.u[1] = pp[(4 * g + 1) * 17 + q];
            pu.u[2] = pp[(4 * g + 2) * 17 + q];
            pu.u[3] = pp[(4 * g + 3) * 17 + q];
            __builtin_amdgcn_wave_barrier();
            bf16x8 va0 = *(const bf16x8*)(Vt + ((size_t)(h * 32 + q)) * NN + mb + g * 8);
            bf16x8 va1 = *(const bf16x8*)(Vt + ((size_t)(h * 32 + 16 + q)) * NN + mb + g * 8);
            o[h][0] = __builtin_amdgcn_mfma_f32_16x16x32_bf16(va0, pu.v, o[h][0], 0, 0, 0);
            o[h][1] = __builtin_amdgcn_mfma_f32_16x16x32_bf16(va1, pu.v, o[h][1], 0, 0, 0);
        }
        // amean write: lane owns row n0+q, m = mb + 4g(+16)
        float4 a0, a1;
        a0.x = am[0] * 0.125f; a0.y = am[1] * 0.125f;
        a0.z = am[2] * 0.125f; a0.w = am[3] * 0.125f;
        a1.x = am[4] * 0.125f; a1.y = am[5] * 0.125f;
        a1.z = am[6] * 0.125f; a1.w = am[7] * 0.125f;
        *(float4*)(amean + (size_t)(n0 + q) * NN + mb + 4 * g) = a0;
        *(float4*)(amean + (size_t)(n0 + q) * NN + mb + 16 + 4 * g) = a1;
    }

    // -------- block reduce O across the 4 waves (2-stage, 33 KB LDS) ------
    if (w < 2) {
        #pragma unroll
        for (int h = 0; h < 8; ++h) {
            #pragma unroll
            for (int dt = 0; dt < 2; ++dt)
                *(f32x4*)&Ow[w * 4160 + q * 260 + h * 32 + dt * 16 + 4 * g] = o[h][dt];
        }
    }
    __syncthreads();
    if (w >= 2) {
        #pragma unroll
        for (int h = 0; h < 8; ++h) {
            #pragma unroll
            for (int dt = 0; dt < 2; ++dt) {
                f32x4* p = (f32x4*)&Ow[(w - 2) * 4160 + q * 260 + h * 32 + dt * 16 + 4 * g];
                *p = *p + o[h][dt];
            }
        }
    }
    __syncthreads();
    for (int i = t; i < 4096; i += 256) {
        int n = i >> 8, c = i & 255;
        float v = Ow[n * 260 + c] + Ow[4160 + n * 260 + c];
        Opart[((size_t)msg * NN + n0 + n) * 256 + c] = v;
    }
}

// -------- finalize: routed = (sum_msg Opart) @ Wo + bo --------------------
__global__ __launch_bounds__(256) void final_kernel(
    const float* __restrict__ accpart, const float* __restrict__ Wo,
    const float* __restrict__ bo, float* __restrict__ routed)
{
    __shared__ float sacc[32 * 257];
    const int nb = blockIdx.x, t = threadIdx.x;
    for (int i = t; i < 8192; i += 256) {
        int r = i >> 8, c = i & 255;
        int n = nb * 32 + r;
        float s = 0.f;
        #pragma unroll
        for (int ms = 0; ms < 4; ++ms)
            s += accpart[((size_t)ms * NN + n) * 256 + c];
        sacc[r * 257 + c] = s;
    }
    __syncthreads();
    const int j = t & 31, r0 = t >> 5;
    #pragma unroll
    for (int rr = 0; rr < 4; ++rr) {
        int r = r0 * 4 + rr;
        float s = bo[j];
        for (int i = 0; i < 256; ++i) s += sacc[r * 257 + i] * Wo[i * 32 + j];
        routed[(size_t)(nb * 32 + r) * 32 + j] = s;
    }
}

extern "C" void kernel_launch(void* const* d_in, const int* in_sizes, int n_in,
                              void* d_out, int out_size, void* d_ws, size_t ws_size,
                              hipStream_t stream) {
    const float* nf  = (const float*)d_in[0];
    const float* msg = (const float*)d_in[1];
    const int*   adj = (const int*)d_in[2];
    const float* Wq  = (const float*)d_in[3];
    const float* bq  = (const float*)d_in[4];
    const float* Wk  = (const float*)d_in[5];
    const float* bk  = (const float*)d_in[6];
    const float* Wv  = (const float*)d_in[7];
    const float* bv  = (const float*)d_in[8];
    const float* Wo  = (const float*)d_in[9];
    const float* bo  = (const float*)d_in[10];

    float* routed = (float*)d_out;
    float* amean  = (float*)d_out + (size_t)NN * MD;

    float* ws = (float*)d_ws;
    // region 0..4194304: Qf/Kf/Vf (dead after packs), then reused as Opart
    float* Qf = ws;                       // 1048576
    float* Kf = ws + 1048576;             // 1048576
    float* Vf = ws + 2097152;             // 1048576
    float* Opart = ws;                    // 4*4096*256 = 4194304 (aliases Qf/Kf/Vf)
    unsigned short* Qb = (unsigned short*)(ws + 4194304);   // 2MB
    unsigned short* Kb = (unsigned short*)(ws + 4718592);   // 2MB
    unsigned short* Vt = (unsigned short*)(ws + 5242880);   // 2MB
    unsigned int*   ab32 = (unsigned int*)(ws + 5767168);   // 2MB
    unsigned long long* ab64 = (unsigned long long*)(ws + 5767168);
    float* Lpart = ws + 6291456;          // 16*8*4096 = 524288
    float* Linv  = ws + 6815744;          // 32768

    proj_kernel<<<384, 256, 0, stream>>>(nf, msg, Wq, bq, Wk, bk, Wv, bv, Qf, Kf, Vf);
    abit_kernel<<<1024, 256, 0, stream>>>(adj, ab64);
    pack_qk<<<1024, 256, 0, stream>>>(Qf, Kf, Qb, Kb);
    pack_vt<<<256, 256, 0, stream>>>(Vf, Vt);
    sweep1_kernel<<<dim3(256, 4), 256, 0, stream>>>(Qb, Kb, ab32, Lpart);
    linv_kernel<<<128, 256, 0, stream>>>(Lpart, Linv);
    sweep2_kernel<<<dim3(256, 4), 256, 0, stream>>>(Qb, Kb, Vt, ab32, Linv, Opart, amean);
    final_kernel<<<128, 256, 0, stream>>>(Opart, Wo, bo, routed);
}